// Round 14
// baseline (197.494 us; speedup 1.0000x reference)
//
#include <hip/hip_runtime.h>
#include <hip/hip_bf16.h>
#include <math.h>

#define B_G   128
#define N0    512
#define DEG   8
#define CCH   128
#define EPG   (N0*DEG)            // 4096 edges per graph (fixed slab)
#define E_TOTAL (B_G*EPG)
#define K1    410
#define K2    328
#define K3    263
#define NCLS  10

using bf16x8 = __attribute__((ext_vector_type(8))) __bf16;
using f32x4  = __attribute__((ext_vector_type(4))) float;
typedef unsigned short ushort;
typedef unsigned int uint;

__device__ __forceinline__ ushort f2b(float f) {
    uint u = __float_as_uint(f);
    u += 0x7fffu + ((u >> 16) & 1u);      // RNE
    return (ushort)(u >> 16);
}
__device__ __forceinline__ float b2f(ushort h) {
    return __uint_as_float(((uint)h) << 16);
}
// split fp32 -> (hi, lo) bf16 pair;  v ~= hi + lo  (error ~2^-17 rel)
__device__ __forceinline__ void split2(float v, ushort& hi, ushort& lo) {
    hi = f2b(v);
    lo = f2b(v - b2f(hi));
}
// packed channel word: hi | lo<<16
__device__ __forceinline__ uint pksplit(float v) {
    ushort h, l; split2(v, h, l);
    return (uint)h | ((uint)l << 16);
}
__device__ __forceinline__ float unpk(uint u) {
    return __uint_as_float(u << 16) + __uint_as_float(u & 0xffff0000u);
}
__device__ __forceinline__ float keyval(unsigned long long key) {
    uint tu = (uint)(key >> 32);
    uint su = (tu & 0x80000000u) ? (tu & 0x7fffffffu) : ~tu;
    return __uint_as_float(su);
}

// ---------------- setup: layer-0 CSR (blocks 0..B_G-1) | pack weights ----------------
__global__ __launch_bounds__(512) void setup_kernel(
        const float* __restrict__ Wrel0, const float* __restrict__ Wroot0,
        const float* __restrict__ Wrel1, const float* __restrict__ Wroot1,
        const float* __restrict__ Wrel2, const float* __restrict__ Wroot2,
        ushort* __restrict__ Bph, ushort* __restrict__ Bpl,
        const int* __restrict__ es, const int* __restrict__ ed,
        int* __restrict__ indptr0, int* __restrict__ counts0, ushort* __restrict__ srclist0) {
    __shared__ uint epk[EPG];     // 16 KB
    __shared__ int cnt[512], pref[512], curs[512];
    if (blockIdx.x < B_G) {
        int b = blockIdx.x, tid = threadIdx.x;
        cnt[tid] = 0;
        __syncthreads();
        int base = b * EPG;
        for (int i = tid; i < EPG; i += 512) {
            int s = es[base + i] & (N0 - 1);
            int d = ed[base + i] & (N0 - 1);
            epk[i] = (uint)s | ((uint)d << 16);
            atomicAdd(&cnt[d], 1);
        }
        __syncthreads();
        pref[tid] = cnt[tid];
        __syncthreads();
        for (int off = 1; off < 512; off <<= 1) {
            int v = (tid >= off) ? pref[tid - off] : 0;
            __syncthreads();
            pref[tid] += v;
            __syncthreads();
        }
        int excl = tid ? pref[tid - 1] : 0;
        indptr0[b * N0 + tid] = base + excl;
        counts0[b * N0 + tid] = cnt[tid];
        curs[tid] = excl;
        __syncthreads();
        for (int i = tid; i < EPG; i += 512) {
            uint wv = epk[i];
            int dl = wv >> 16;
            int pos = atomicAdd(&curs[dl], 1);
            srclist0[base + pos] = (ushort)(wv & 0xFFFFu);
        }
    } else {
        int i = (blockIdx.x - B_G) * 512 + threadIdx.x;
        if (i < 3 * 32768) {
            int layer = i >> 15, rem = i & 32767;
            int j = rem & 7, lane = (rem >> 3) & 63, cf = (rem >> 9) & 7, ks = rem >> 12;
            int k = ks * 32 + (lane >> 4) * 8 + j;
            int c = cf * 16 + (lane & 15);
            const float* Wrel  = layer == 0 ? Wrel0  : layer == 1 ? Wrel1  : Wrel2;
            const float* Wroot = layer == 0 ? Wroot0 : layer == 1 ? Wroot1 : Wroot2;
            float v = (k < 128) ? Wrel[k * 128 + c] : Wroot[(k - 128) * 128 + c];
            ushort hi, lo; split2(v, hi, lo);
            Bph[i] = hi; Bpl[i] = lo;
        }
    }
}

// ---------------- layer-0 aggregation: fp32 x0 direct, LDS slab stride 32 ----------------
__global__ __launch_bounds__(1024) void aggregate0(
        const float* __restrict__ xf,
        const int* __restrict__ indptr, const int* __restrict__ counts,
        const ushort* __restrict__ srclist,
        uint* __restrict__ aggp) {
    extern __shared__ float slab[];            // [512][32] fp32
    int b = blockIdx.x >> 2, q = blockIdx.x & 3;
    int tid = threadIdx.x;
    const float4* xf4 = (const float4*)xf;     // row = 32 float4s
    for (int t = tid; t < N0 * 8; t += 1024) {
        int nd = t >> 3, c4 = t & 7;
        float4 u = xf4[(size_t)(b * N0 + nd) * 32 + q * 8 + c4];
        *(float4*)&slab[nd * 32 + c4 * 4] = u;
    }
    __syncthreads();
    int wave = tid >> 6, lane = tid & 63;
    int gl = lane >> 3, sub = lane & 7;
    for (int g = wave; g < N0 / 8; g += 16) {
        int d = g * 8 + gl;
        int beg = indptr[b * N0 + d];
        int cnt = counts[b * N0 + d];
        float4 acc = make_float4(0.f, 0.f, 0.f, 0.f);
        int id_next = (cnt > 0) ? (int)srclist[beg] : 0;
        for (int j = 0; j < cnt; j++) {
            int id = id_next;
            if (j + 1 < cnt) id_next = (int)srclist[beg + j + 1];
            const float4 v = *(const float4*)&slab[id * 32 + sub * 4];
            acc.x += v.x; acc.y += v.y; acc.z += v.z; acc.w += v.w;
        }
        uint4 o;
        o.x = pksplit(acc.x); o.y = pksplit(acc.y);
        o.z = pksplit(acc.z); o.w = pksplit(acc.w);
        *(uint4*)&aggp[(size_t)(b * N0 + d) * CCH + q * 32 + sub * 4] = o;
    }
}

// ---------------- bf16x3 MFMA transform + fused score (LDS-staged B) ----------------
// root operand: rootf (fp32, layer 0) OR hin packed with perm+pval (layers 1,2)
__global__ __launch_bounds__(512, 4) void transform_mfma(
        const uint* __restrict__ aggp, const uint* __restrict__ hin,
        const float* __restrict__ rootf,
        const int* __restrict__ perm, const float* __restrict__ pval,
        const ushort* __restrict__ Bph, const ushort* __restrict__ Bpl,
        const float* __restrict__ brel, const float* __restrict__ pvec,
        uint* __restrict__ hout, float* __restrict__ score) {
    __shared__ ushort ldsBh[16384];   // 32 KB: [4 ks][8 cf][64 lane][8]
    __shared__ ushort ldsBl[16384];   // 32 KB
    int tid = threadIdx.x;
    int wave = tid >> 6, lane = tid & 63;
    int r = lane & 15, kb = lane >> 4;
    int rows0 = blockIdx.x * 128 + wave * 16;
    int gid = rows0 + r;
    size_t oldrow = perm ? (size_t)perm[gid] : (size_t)gid;
    float rv = perm ? pval[gid] : 1.f;

    f32x4 acc[8];
#pragma unroll
    for (int cf = 0; cf < 8; cf++) acc[cf] = (f32x4)(0.f);

    union U16 { uint u[4]; bf16x8 v; };

#pragma unroll
    for (int half = 0; half < 2; half++) {
        if (half) __syncthreads();
#pragma unroll
        for (int i = 0; i < 4; i++) {
            int idx = tid + i * 512;
            ((uint4*)ldsBh)[idx] = ((const uint4*)(Bph + half * 16384))[idx];
            ((uint4*)ldsBl)[idx] = ((const uint4*)(Bpl + half * 16384))[idx];
        }
        __syncthreads();
#pragma unroll
        for (int ks4 = 0; ks4 < 4; ks4++) {
            U16 ah, al;
            if (half && rootf) {
                const float* R = rootf + (size_t)gid * CCH + ks4 * 32 + kb * 8;
                float4 f0 = *(const float4*)R;
                float4 f1 = *(const float4*)(R + 4);
                float c[8] = {f0.x, f0.y, f0.z, f0.w, f1.x, f1.y, f1.z, f1.w};
#pragma unroll
                for (int p2 = 0; p2 < 4; p2++) {
                    ushort h0, l0, h1, l1;
                    split2(c[2 * p2], h0, l0);
                    split2(c[2 * p2 + 1], h1, l1);
                    ah.u[p2] = (uint)h0 | ((uint)h1 << 16);
                    al.u[p2] = (uint)l0 | ((uint)l1 << 16);
                }
            } else {
                const uint* A = half ? hin : aggp;
                size_t abase = half ? oldrow * CCH : (size_t)gid * CCH;
                size_t rowbase = abase + ks4 * 32 + kb * 8;
                uint4 ua = *(const uint4*)&A[rowbase];
                uint4 ub = *(const uint4*)&A[rowbase + 4];
                if (half && perm) {
                    float c[8] = {unpk(ua.x) * rv, unpk(ua.y) * rv, unpk(ua.z) * rv,
                                  unpk(ua.w) * rv, unpk(ub.x) * rv, unpk(ub.y) * rv,
                                  unpk(ub.z) * rv, unpk(ub.w) * rv};
#pragma unroll
                    for (int p2 = 0; p2 < 4; p2++) {
                        ushort h0, l0, h1, l1;
                        split2(c[2 * p2], h0, l0);
                        split2(c[2 * p2 + 1], h1, l1);
                        ah.u[p2] = (uint)h0 | ((uint)h1 << 16);
                        al.u[p2] = (uint)l0 | ((uint)l1 << 16);
                    }
                } else {
                    ah.u[0] = (ua.x & 0xffffu) | (ua.y << 16);
                    ah.u[1] = (ua.z & 0xffffu) | (ua.w << 16);
                    ah.u[2] = (ub.x & 0xffffu) | (ub.y << 16);
                    ah.u[3] = (ub.z & 0xffffu) | (ub.w << 16);
                    al.u[0] = (ua.x >> 16) | (ua.y & 0xffff0000u);
                    al.u[1] = (ua.z >> 16) | (ua.w & 0xffff0000u);
                    al.u[2] = (ub.x >> 16) | (ub.y & 0xffff0000u);
                    al.u[3] = (ub.z >> 16) | (ub.w & 0xffff0000u);
                }
            }
#pragma unroll
            for (int cf = 0; cf < 8; cf++) {
                bf16x8 bh = *(const bf16x8*)&ldsBh[((ks4 * 8 + cf) * 64 + lane) * 8];
                bf16x8 bl = *(const bf16x8*)&ldsBl[((ks4 * 8 + cf) * 64 + lane) * 8];
                acc[cf] = __builtin_amdgcn_mfma_f32_16x16x32_bf16(ah.v, bl, acc[cf], 0, 0, 0);
                acc[cf] = __builtin_amdgcn_mfma_f32_16x16x32_bf16(al.v, bh, acc[cf], 0, 0, 0);
                acc[cf] = __builtin_amdgcn_mfma_f32_16x16x32_bf16(ah.v, bh, acc[cf], 0, 0, 0);
            }
        }
    }

    // epilogue: bias+relu (fp32), packed store, fused score
    float pv[8], bb[8], q = 0.f;
#pragma unroll
    for (int cf = 0; cf < 8; cf++) {
        pv[cf] = pvec[cf * 16 + r];
        bb[cf] = brel[cf * 16 + r];
        q += pv[cf] * pv[cf];
    }
    float dots[4] = {0.f, 0.f, 0.f, 0.f};
#pragma unroll
    for (int cf = 0; cf < 8; cf++) {
#pragma unroll
        for (int reg = 0; reg < 4; reg++) {
            float v = acc[cf][reg] + bb[cf];
            v = v > 0.f ? v : 0.f;
            hout[(size_t)(rows0 + kb * 4 + reg) * CCH + cf * 16 + r] = pksplit(v);
            dots[reg] += v * pv[cf];
        }
    }
#pragma unroll
    for (int off = 1; off < 16; off <<= 1) {
        q += __shfl_xor(q, off);
#pragma unroll
        for (int reg = 0; reg < 4; reg++) dots[reg] += __shfl_xor(dots[reg], off);
    }
    if (r == 0) {
        float inv_norm = rsqrtf(q);
#pragma unroll
        for (int reg = 0; reg < 4; reg++)
            score[rows0 + kb * 4 + reg] = tanhf(dots[reg] * inv_norm);
    }
}

// ---------------- fused pool + next-layer aggregation (4 blocks/graph, 1024 thr) ----------------
__global__ __launch_bounds__(1024) void poolagg_kernel(
        const float* __restrict__ score, const uint* __restrict__ hp,
        int* __restrict__ perm_out, float* __restrict__ pval_out,
        float* __restrict__ gpart,           // this layer's [B_G][256] slice
        const int* __restrict__ ipt_in, const int* __restrict__ cnt_in,
        const ushort* __restrict__ src_in,
        int* __restrict__ ipt_out, int* __restrict__ cnt_out,
        ushort* __restrict__ src_out,
        uint* __restrict__ aggout,
        int n, int k, int do_agg) {
    int b = blockIdx.x >> 2, q = blockIdx.x & 3;
    int tid = threadIdx.x;
    __shared__ unsigned long long keys[512];
    __shared__ short invl[512];
    __shared__ int prefL[512];
    __shared__ ushort srcIn[EPG];        // 8 KB: input CSR edges (local src ids)
    __shared__ float wredbuf[2048];      // 8 KB: readout partials, then srcOut
    ushort* srcOut = (ushort*)wredbuf;
    extern __shared__ float slab[];      // [k][32] fp32, scaled pooled features

    // 1. key load + coalesced srcIn copy
    if (tid < 512) {
        unsigned long long key = 0ull;
        if (tid < n) {
            uint u = __float_as_uint(score[b * n + tid]);
            u = (u & 0x80000000u) ? ~u : (u | 0x80000000u);
            key = ((unsigned long long)u << 32) | (uint)(~tid);
        }
        keys[tid] = key;
        invl[tid] = -1;
    }
    if (do_agg) {
        const uint* s4 = (const uint*)(src_in + b * EPG);
        uint* d4 = (uint*)srcIn;
        for (int i = tid; i < EPG / 2; i += 1024) d4[i] = s4[i];
    }
    __syncthreads();
    // 2. bitonic sort, descending (deterministic -> identical across the 4 blocks)
    for (int kk2 = 2; kk2 <= 512; kk2 <<= 1) {
        for (int j = kk2 >> 1; j > 0; j >>= 1) {
            if (tid < 512) {
                int s = tid, sxj = s ^ j;
                if (sxj > s) {
                    unsigned long long a = keys[s], c = keys[sxj];
                    bool doSwap = ((s & kk2) == 0) ? (a < c) : (a > c);
                    if (doSwap) { keys[s] = c; keys[sxj] = a; }
                }
            }
            __syncthreads();
        }
    }
    if (tid < k) {
        int node = (int)(~(uint)keys[tid]);
        invl[node] = (short)tid;
    }
    __syncthreads();
    // 3. stage slab: scaled pooled rows, quarter channels
    for (int t = tid; t < k * 8; t += 1024) {
        int nd = t >> 3, c4 = t & 7;
        unsigned long long key = keys[nd];
        int node = (int)(~(uint)key);
        float v = keyval(key);
        uint4 u = *(const uint4*)&hp[(size_t)(b * n + node) * CCH + q * 32 + c4 * 4];
        *(float4*)&slab[nd * 32 + c4 * 4] =
            make_float4(unpk(u.x) * v, unpk(u.y) * v, unpk(u.z) * v, unpk(u.w) * v);
    }
    __syncthreads();
    // 4. readout from slab: 32 channels x 32 workers (2-way LDS, free)
    {
        int w = tid >> 5, ch = tid & 31;
        float mx = -1e30f, sm = 0.f;
        for (int r2 = w; r2 < k; r2 += 32) {
            float v = slab[r2 * 32 + ch];
            mx = fmaxf(mx, v); sm += v;
        }
        wredbuf[w * 32 + ch] = mx;
        wredbuf[1024 + w * 32 + ch] = sm;
    }
    __syncthreads();
    if (tid < 32) {
        float m = -1e30f, s = 0.f;
        for (int w = 0; w < 32; w++) {
            m = fmaxf(m, wredbuf[w * 32 + tid]);
            s += wredbuf[1024 + w * 32 + tid];
        }
        gpart[b * 256 + q * 32 + tid] = m;
        gpart[b * 256 + 128 + q * 32 + tid] = s / (float)k;
    }
    if (!do_agg) return;
    __syncthreads();   // wredbuf reads done; srcOut may now overwrite it
    // 5. compaction count (from LDS srcIn)
    int node = -1, beg = 0, c = 0, nk = 0;
    if (tid < k) {
        node = (int)(~(uint)keys[tid]);
        beg = ipt_in[b * n + node] - b * EPG;
        c = cnt_in[b * n + node];
        for (int t = 0; t < c; t++)
            if (invl[srcIn[beg + t]] >= 0) nk++;
    }
    if (tid < 512) prefL[tid] = (tid < k) ? nk : 0;
    __syncthreads();
    for (int off = 1; off < 512; off <<= 1) {
        int v = (tid >= off && tid < 512) ? prefL[tid - off] : 0;
        __syncthreads();
        if (tid < 512) prefL[tid] += v;
        __syncthreads();
    }
    int excl = (tid < 512 && tid) ? prefL[tid - 1] : 0;
    // 6. scatter srcOut (LDS)
    if (tid < k) {
        int pos = excl;
        for (int t = 0; t < c; t++) {
            int ns = invl[srcIn[beg + t]];
            if (ns >= 0) srcOut[pos++] = (ushort)ns;
        }
    }
    __syncthreads();
    // 7. q==0 writes global CSR + perm/pval
    if (q == 0) {
        int tot = prefL[511];
        if (tid < k) {
            ipt_out[b * k + tid] = b * EPG + excl;
            cnt_out[b * k + tid] = nk;
            perm_out[b * k + tid] = b * n + node;
            pval_out[b * k + tid] = keyval(keys[tid]);
        }
        for (int i = tid; i < tot; i += 1024) src_out[b * EPG + i] = srcOut[i];
    }
    // 8. edge-aggregate next layer from slab (LDS CSR), 16 waves, prefetched
    {
        int wave = tid >> 6, lane = tid & 63;
        int gl = lane >> 3, sub = lane & 7;
        int ngroups = (k + 7) >> 3;
        for (int g = wave; g < ngroups; g += 16) {
            int d = g * 8 + gl;
            bool act = d < k;
            int bg = 0, en = 0;
            if (act) { bg = d ? prefL[d - 1] : 0; en = prefL[d]; }
            int cc = en - bg;
            float4 acc = make_float4(0.f, 0.f, 0.f, 0.f);
            int id_next = (cc > 0) ? (int)srcOut[bg] : 0;
            for (int j = 0; j < cc; j++) {
                int id = id_next;
                if (j + 1 < cc) id_next = (int)srcOut[bg + j + 1];
                const float4 v = *(const float4*)&slab[id * 32 + sub * 4];
                acc.x += v.x; acc.y += v.y; acc.z += v.z; acc.w += v.w;
            }
            if (act) {
                uint4 o;
                o.x = pksplit(acc.x); o.y = pksplit(acc.y);
                o.z = pksplit(acc.z); o.w = pksplit(acc.w);
                *(uint4*)&aggout[(size_t)(b * k + d) * CCH + q * 32 + sub * 4] = o;
            }
        }
    }
}

// ---------------- final MLP + log_softmax ----------------
__global__ __launch_bounds__(128) void mlp_kernel(const float* __restrict__ gpart,
        const float* __restrict__ W1, const float* __restrict__ b1,
        const float* __restrict__ W2, const float* __restrict__ b2,
        const float* __restrict__ W3, const float* __restrict__ b3,
        float* __restrict__ out) {
    int b = blockIdx.x, t = threadIdx.x;
    __shared__ float gs[256], h1[128], h2[64], lg[10];
    const float* g0 = gpart + ((size_t)0 * B_G + b) * 256;
    const float* g1 = gpart + ((size_t)1 * B_G + b) * 256;
    const float* g2 = gpart + ((size_t)2 * B_G + b) * 256;
    gs[t] = g0[t] + g1[t] + g2[t];
    gs[128 + t] = g0[128 + t] + g1[128 + t] + g2[128 + t];
    __syncthreads();
    {
        float a = b1[t];
        for (int c = 0; c < 256; c++) a += gs[c] * W1[c * 128 + t];
        h1[t] = fmaxf(a, 0.f);
    }
    __syncthreads();
    if (t < 64) {
        float a = b2[t];
        for (int c = 0; c < 128; c++) a += h1[c] * W2[c * 64 + t];
        h2[t] = fmaxf(a, 0.f);
    }
    __syncthreads();
    if (t < 10) {
        float a = b3[t];
        for (int c = 0; c < 64; c++) a += h2[c] * W3[c * 10 + t];
        lg[t] = a;
    }
    __syncthreads();
    if (t < 10) {
        float m = lg[0];
        for (int i = 1; i < 10; i++) m = fmaxf(m, lg[i]);
        float s = 0.f;
        for (int i = 0; i < 10; i++) s += expf(lg[i] - m);
        out[b * 10 + t] = lg[t] - m - logf(s);
    }
}

// ---------------- host ----------------
extern "C" void kernel_launch(void* const* d_in, const int* in_sizes, int n_in,
                              void* d_out, int out_size, void* d_ws, size_t ws_size,
                              hipStream_t stream) {
    (void)in_sizes; (void)n_in; (void)out_size; (void)ws_size;
    const float* x0 = (const float*)d_in[0];
    const int* es = (const int*)d_in[1];
    const int* ed = (const int*)d_in[2];
    const float* Wroot[3] = {(const float*)d_in[3], (const float*)d_in[7], (const float*)d_in[11]};
    const float* Wrel[3]  = {(const float*)d_in[4], (const float*)d_in[8], (const float*)d_in[12]};
    const float* brel[3]  = {(const float*)d_in[5], (const float*)d_in[9], (const float*)d_in[13]};
    const float* pvec[3]  = {(const float*)d_in[6], (const float*)d_in[10], (const float*)d_in[14]};
    const float* W1 = (const float*)d_in[15];
    const float* b1 = (const float*)d_in[16];
    const float* W2 = (const float*)d_in[17];
    const float* b2 = (const float*)d_in[18];
    const float* W3 = (const float*)d_in[19];
    const float* b3 = (const float*)d_in[20];

    size_t off = 0;
    char* base = (char*)d_ws;
    auto alloc = [&](size_t bytes) -> void* {
        void* p = base + off;
        off += (bytes + 255) & ~(size_t)255;
        return p;
    };
    const size_t FEATP = (size_t)(B_G * N0) * CCH * 4;   // packed uint plane
    uint* P0 = (uint*)alloc(FEATP);          // h planes / agg plane rotate
    uint* P1 = (uint*)alloc(FEATP);
    uint* P2 = (uint*)alloc(FEATP);
    ushort* Bph = (ushort*)alloc((size_t)3 * 32768 * 2);
    ushort* Bpl = (ushort*)alloc((size_t)3 * 32768 * 2);
    int* iptA = (int*)alloc((size_t)(B_G * N0) * 4);
    int* cntA = (int*)alloc((size_t)(B_G * N0) * 4);
    ushort* srcA = (ushort*)alloc((size_t)E_TOTAL * 2);
    int* iptB = (int*)alloc((size_t)(B_G * N0) * 4);
    int* cntB = (int*)alloc((size_t)(B_G * N0) * 4);
    ushort* srcB = (ushort*)alloc((size_t)E_TOTAL * 2);
    int* permA = (int*)alloc((size_t)(B_G * K1) * 4);
    float* pvalA = (float*)alloc((size_t)(B_G * K1) * 4);
    int* permB = (int*)alloc((size_t)(B_G * K1) * 4);
    float* pvalB = (float*)alloc((size_t)(B_G * K1) * 4);
    float* score = (float*)alloc((size_t)(B_G * N0) * 4);
    float* gpart = (float*)alloc((size_t)3 * B_G * 256 * 4);

    // setup: CSR0 + weight pack
    setup_kernel<<<B_G + (3 * 32768 + 511) / 512, 512, 0, stream>>>(
        Wrel[0], Wroot[0], Wrel[1], Wroot[1], Wrel[2], Wroot[2],
        Bph, Bpl, es, ed, iptA, cntA, srcA);

    // L0: agg from fp32 x0 -> P1 ; tf (root = fp32 x0) -> h0 in P0, score
    aggregate0<<<4 * B_G, 1024, (size_t)N0 * 32 * 4, stream>>>(
        x0, iptA, cntA, srcA, P1);
    transform_mfma<<<B_G * N0 / 128, 512, 0, stream>>>(
        P1, nullptr, x0, nullptr, nullptr, Bph, Bpl, brel[0], pvec[0], P0, score);
    // pool L0 + agg L1 -> P1 ; CSR A->B ; perm/pval A
    poolagg_kernel<<<4 * B_G, 1024, (size_t)K1 * 32 * 4, stream>>>(
        score, P0, permA, pvalA, gpart + (size_t)0 * B_G * 256,
        iptA, cntA, srcA, iptB, cntB, srcB, P1, N0, K1, 1);

    // L1: tf (A=P1, root=P0 via permA) -> h1 in P2, score
    transform_mfma<<<B_G * K1 / 128, 512, 0, stream>>>(
        P1, P0, nullptr, permA, pvalA, Bph + 32768, Bpl + 32768,
        brel[1], pvec[1], P2, score);
    // pool L1 + agg L2 -> P1 ; CSR B->A ; perm/pval B
    poolagg_kernel<<<4 * B_G, 1024, (size_t)K2 * 32 * 4, stream>>>(
        score, P2, permB, pvalB, gpart + (size_t)1 * B_G * 256,
        iptB, cntB, srcB, iptA, cntA, srcA, P1, K1, K2, 1);

    // L2: tf (A=P1, root=P2 via permB) -> h2 in P0, score
    transform_mfma<<<B_G * K2 / 128, 512, 0, stream>>>(
        P1, P2, nullptr, permB, pvalB, Bph + 2 * 32768, Bpl + 2 * 32768,
        brel[2], pvec[2], P0, score);
    // final pool: readout only
    poolagg_kernel<<<4 * B_G, 1024, (size_t)K3 * 32 * 4, stream>>>(
        score, P0, nullptr, nullptr, gpart + (size_t)2 * B_G * 256,
        iptA, cntA, srcA, nullptr, nullptr, nullptr, nullptr, K2, K3, 0);

    mlp_kernel<<<B_G, 128, 0, stream>>>(gpart, W1, b1, W2, b2, W3, b3, (float*)d_out);
}

// Round 15
// 196.498 us; speedup vs baseline: 1.0051x; 1.0051x over previous
//
#include <hip/hip_runtime.h>
#include <hip/hip_bf16.h>
#include <math.h>

#define B_G   128
#define N0    512
#define DEG   8
#define CCH   128
#define EPG   (N0*DEG)            // 4096 edges per graph (fixed slab)
#define E_TOTAL (B_G*EPG)
#define K1    410
#define K2    328
#define K3    263
#define NCLS  10

using bf16x8 = __attribute__((ext_vector_type(8))) __bf16;
using f32x4  = __attribute__((ext_vector_type(4))) float;
typedef unsigned short ushort;
typedef unsigned int uint;
typedef unsigned long long u64;

__device__ __forceinline__ ushort f2b(float f) {
    uint u = __float_as_uint(f);
    u += 0x7fffu + ((u >> 16) & 1u);      // RNE
    return (ushort)(u >> 16);
}
__device__ __forceinline__ float b2f(ushort h) {
    return __uint_as_float(((uint)h) << 16);
}
// split fp32 -> (hi, lo) bf16 pair;  v ~= hi + lo  (error ~2^-17 rel)
__device__ __forceinline__ void split2(float v, ushort& hi, ushort& lo) {
    hi = f2b(v);
    lo = f2b(v - b2f(hi));
}
// packed channel word: hi | lo<<16
__device__ __forceinline__ uint pksplit(float v) {
    ushort h, l; split2(v, h, l);
    return (uint)h | ((uint)l << 16);
}
__device__ __forceinline__ float unpk(uint u) {
    return __uint_as_float(u << 16) + __uint_as_float(u & 0xffff0000u);
}
__device__ __forceinline__ float keyval(u64 key) {
    uint tu = (uint)(key >> 32);
    uint su = (tu & 0x80000000u) ? (tu & 0x7fffffffu) : ~tu;
    return __uint_as_float(su);
}

// ---------------- setup: layer-0 CSR (blocks 0..B_G-1) | pack weights ----------------
__global__ __launch_bounds__(512) void setup_kernel(
        const float* __restrict__ Wrel0, const float* __restrict__ Wroot0,
        const float* __restrict__ Wrel1, const float* __restrict__ Wroot1,
        const float* __restrict__ Wrel2, const float* __restrict__ Wroot2,
        ushort* __restrict__ Bph, ushort* __restrict__ Bpl,
        const int* __restrict__ es, const int* __restrict__ ed,
        int* __restrict__ indptr0, int* __restrict__ counts0, ushort* __restrict__ srclist0) {
    __shared__ uint epk[EPG];     // 16 KB
    __shared__ int cnt[512], pref[512], curs[512];
    if (blockIdx.x < B_G) {
        int b = blockIdx.x, tid = threadIdx.x;
        cnt[tid] = 0;
        __syncthreads();
        int base = b * EPG;
        for (int i = tid; i < EPG; i += 512) {
            int s = es[base + i] & (N0 - 1);
            int d = ed[base + i] & (N0 - 1);
            epk[i] = (uint)s | ((uint)d << 16);
            atomicAdd(&cnt[d], 1);
        }
        __syncthreads();
        pref[tid] = cnt[tid];
        __syncthreads();
        for (int off = 1; off < 512; off <<= 1) {
            int v = (tid >= off) ? pref[tid - off] : 0;
            __syncthreads();
            pref[tid] += v;
            __syncthreads();
        }
        int excl = tid ? pref[tid - 1] : 0;
        indptr0[b * N0 + tid] = base + excl;
        counts0[b * N0 + tid] = cnt[tid];
        curs[tid] = excl;
        __syncthreads();
        for (int i = tid; i < EPG; i += 512) {
            uint wv = epk[i];
            int dl = wv >> 16;
            int pos = atomicAdd(&curs[dl], 1);
            srclist0[base + pos] = (ushort)(wv & 0xFFFFu);
        }
    } else {
        int i = (blockIdx.x - B_G) * 512 + threadIdx.x;
        if (i < 3 * 32768) {
            int layer = i >> 15, rem = i & 32767;
            int j = rem & 7, lane = (rem >> 3) & 63, cf = (rem >> 9) & 7, ks = rem >> 12;
            int k = ks * 32 + (lane >> 4) * 8 + j;
            int c = cf * 16 + (lane & 15);
            const float* Wrel  = layer == 0 ? Wrel0  : layer == 1 ? Wrel1  : Wrel2;
            const float* Wroot = layer == 0 ? Wroot0 : layer == 1 ? Wroot1 : Wroot2;
            float v = (k < 128) ? Wrel[k * 128 + c] : Wroot[(k - 128) * 128 + c];
            ushort hi, lo; split2(v, hi, lo);
            Bph[i] = hi; Bpl[i] = lo;
        }
    }
}

// ---------------- layer-0 aggregation: fp32 x0 direct, LDS slab stride 32 ----------------
__global__ __launch_bounds__(1024) void aggregate0(
        const float* __restrict__ xf,
        const int* __restrict__ indptr, const int* __restrict__ counts,
        const ushort* __restrict__ srclist,
        uint* __restrict__ aggp) {
    extern __shared__ float slab[];            // [512][32] fp32
    int b = blockIdx.x >> 2, q = blockIdx.x & 3;
    int tid = threadIdx.x;
    const float4* xf4 = (const float4*)xf;     // row = 32 float4s
    for (int t = tid; t < N0 * 8; t += 1024) {
        int nd = t >> 3, c4 = t & 7;
        float4 u = xf4[(size_t)(b * N0 + nd) * 32 + q * 8 + c4];
        *(float4*)&slab[nd * 32 + c4 * 4] = u;
    }
    __syncthreads();
    int wave = tid >> 6, lane = tid & 63;
    int gl = lane >> 3, sub = lane & 7;
    for (int g = wave; g < N0 / 8; g += 16) {
        int d = g * 8 + gl;
        int beg = indptr[b * N0 + d];
        int cnt = counts[b * N0 + d];
        float4 acc = make_float4(0.f, 0.f, 0.f, 0.f);
        int id_next = (cnt > 0) ? (int)srclist[beg] : 0;
        for (int j = 0; j < cnt; j++) {
            int id = id_next;
            if (j + 1 < cnt) id_next = (int)srclist[beg + j + 1];
            const float4 v = *(const float4*)&slab[id * 32 + sub * 4];
            acc.x += v.x; acc.y += v.y; acc.z += v.z; acc.w += v.w;
        }
        uint4 o;
        o.x = pksplit(acc.x); o.y = pksplit(acc.y);
        o.z = pksplit(acc.z); o.w = pksplit(acc.w);
        *(uint4*)&aggp[(size_t)(b * N0 + d) * CCH + q * 32 + sub * 4] = o;
    }
}

// ---------------- bf16x3 MFMA transform + fused score (LDS-staged B) ----------------
// root operand: rootf (fp32, layer 0) OR hin packed with perm+pval (layers 1,2)
__global__ __launch_bounds__(512, 4) void transform_mfma(
        const uint* __restrict__ aggp, const uint* __restrict__ hin,
        const float* __restrict__ rootf,
        const int* __restrict__ perm, const float* __restrict__ pval,
        const ushort* __restrict__ Bph, const ushort* __restrict__ Bpl,
        const float* __restrict__ brel, const float* __restrict__ pvec,
        uint* __restrict__ hout, float* __restrict__ score) {
    __shared__ ushort ldsBh[16384];   // 32 KB: [4 ks][8 cf][64 lane][8]
    __shared__ ushort ldsBl[16384];   // 32 KB
    int tid = threadIdx.x;
    int wave = tid >> 6, lane = tid & 63;
    int r = lane & 15, kb = lane >> 4;
    int rows0 = blockIdx.x * 128 + wave * 16;
    int gid = rows0 + r;
    size_t oldrow = perm ? (size_t)perm[gid] : (size_t)gid;
    float rv = perm ? pval[gid] : 1.f;

    f32x4 acc[8];
#pragma unroll
    for (int cf = 0; cf < 8; cf++) acc[cf] = (f32x4)(0.f);

    union U16 { uint u[4]; bf16x8 v; };

#pragma unroll
    for (int half = 0; half < 2; half++) {
        if (half) __syncthreads();
#pragma unroll
        for (int i = 0; i < 4; i++) {
            int idx = tid + i * 512;
            ((uint4*)ldsBh)[idx] = ((const uint4*)(Bph + half * 16384))[idx];
            ((uint4*)ldsBl)[idx] = ((const uint4*)(Bpl + half * 16384))[idx];
        }
        __syncthreads();
#pragma unroll
        for (int ks4 = 0; ks4 < 4; ks4++) {
            U16 ah, al;
            if (half && rootf) {
                const float* R = rootf + (size_t)gid * CCH + ks4 * 32 + kb * 8;
                float4 f0 = *(const float4*)R;
                float4 f1 = *(const float4*)(R + 4);
                float c[8] = {f0.x, f0.y, f0.z, f0.w, f1.x, f1.y, f1.z, f1.w};
#pragma unroll
                for (int p2 = 0; p2 < 4; p2++) {
                    ushort h0, l0, h1, l1;
                    split2(c[2 * p2], h0, l0);
                    split2(c[2 * p2 + 1], h1, l1);
                    ah.u[p2] = (uint)h0 | ((uint)h1 << 16);
                    al.u[p2] = (uint)l0 | ((uint)l1 << 16);
                }
            } else {
                const uint* A = half ? hin : aggp;
                size_t abase = half ? oldrow * CCH : (size_t)gid * CCH;
                size_t rowbase = abase + ks4 * 32 + kb * 8;
                uint4 ua = *(const uint4*)&A[rowbase];
                uint4 ub = *(const uint4*)&A[rowbase + 4];
                if (half && perm) {
                    float c[8] = {unpk(ua.x) * rv, unpk(ua.y) * rv, unpk(ua.z) * rv,
                                  unpk(ua.w) * rv, unpk(ub.x) * rv, unpk(ub.y) * rv,
                                  unpk(ub.z) * rv, unpk(ub.w) * rv};
#pragma unroll
                    for (int p2 = 0; p2 < 4; p2++) {
                        ushort h0, l0, h1, l1;
                        split2(c[2 * p2], h0, l0);
                        split2(c[2 * p2 + 1], h1, l1);
                        ah.u[p2] = (uint)h0 | ((uint)h1 << 16);
                        al.u[p2] = (uint)l0 | ((uint)l1 << 16);
                    }
                } else {
                    ah.u[0] = (ua.x & 0xffffu) | (ua.y << 16);
                    ah.u[1] = (ua.z & 0xffffu) | (ua.w << 16);
                    ah.u[2] = (ub.x & 0xffffu) | (ub.y << 16);
                    ah.u[3] = (ub.z & 0xffffu) | (ub.w << 16);
                    al.u[0] = (ua.x >> 16) | (ua.y & 0xffff0000u);
                    al.u[1] = (ua.z >> 16) | (ua.w & 0xffff0000u);
                    al.u[2] = (ub.x >> 16) | (ub.y & 0xffff0000u);
                    al.u[3] = (ub.z >> 16) | (ub.w & 0xffff0000u);
                }
            }
#pragma unroll
            for (int cf = 0; cf < 8; cf++) {
                bf16x8 bh = *(const bf16x8*)&ldsBh[((ks4 * 8 + cf) * 64 + lane) * 8];
                bf16x8 bl = *(const bf16x8*)&ldsBl[((ks4 * 8 + cf) * 64 + lane) * 8];
                acc[cf] = __builtin_amdgcn_mfma_f32_16x16x32_bf16(ah.v, bl, acc[cf], 0, 0, 0);
                acc[cf] = __builtin_amdgcn_mfma_f32_16x16x32_bf16(al.v, bh, acc[cf], 0, 0, 0);
                acc[cf] = __builtin_amdgcn_mfma_f32_16x16x32_bf16(ah.v, bh, acc[cf], 0, 0, 0);
            }
        }
    }

    // epilogue: bias+relu (fp32), packed store, fused score
    float pv[8], bb[8], q = 0.f;
#pragma unroll
    for (int cf = 0; cf < 8; cf++) {
        pv[cf] = pvec[cf * 16 + r];
        bb[cf] = brel[cf * 16 + r];
        q += pv[cf] * pv[cf];
    }
    float dots[4] = {0.f, 0.f, 0.f, 0.f};
#pragma unroll
    for (int cf = 0; cf < 8; cf++) {
#pragma unroll
        for (int reg = 0; reg < 4; reg++) {
            float v = acc[cf][reg] + bb[cf];
            v = v > 0.f ? v : 0.f;
            hout[(size_t)(rows0 + kb * 4 + reg) * CCH + cf * 16 + r] = pksplit(v);
            dots[reg] += v * pv[cf];
        }
    }
#pragma unroll
    for (int off = 1; off < 16; off <<= 1) {
        q += __shfl_xor(q, off);
#pragma unroll
        for (int reg = 0; reg < 4; reg++) dots[reg] += __shfl_xor(dots[reg], off);
    }
    if (r == 0) {
        float inv_norm = rsqrtf(q);
#pragma unroll
        for (int reg = 0; reg < 4; reg++)
            score[rows0 + kb * 4 + reg] = tanhf(dots[reg] * inv_norm);
    }
}

// ---------------- fused pool + next-layer aggregation (4 blocks/graph, 1024 thr) ----------------
// Sort: register-resident bitonic; in-wave rounds (j<64) via shfl_xor (no barriers),
// cross-wave rounds (j>=64) via LDS. Scan: shfl-based. ~23 barriers vs ~75.
__global__ __launch_bounds__(1024) void poolagg_kernel(
        const float* __restrict__ score, const uint* __restrict__ hp,
        int* __restrict__ perm_out, float* __restrict__ pval_out,
        float* __restrict__ gpart,           // this layer's [B_G][256] slice
        const int* __restrict__ ipt_in, const int* __restrict__ cnt_in,
        const ushort* __restrict__ src_in,
        int* __restrict__ ipt_out, int* __restrict__ cnt_out,
        ushort* __restrict__ src_out,
        uint* __restrict__ aggout,
        int n, int k, int do_agg) {
    int b = blockIdx.x >> 2, q = blockIdx.x & 3;
    int tid = threadIdx.x;
    __shared__ u64 keys[512];
    __shared__ short invl[512];
    __shared__ int prefL[512];
    __shared__ int wtot[8], woff[8];
    __shared__ ushort srcIn[EPG];        // 8 KB: input CSR edges (local src ids)
    __shared__ float wredbuf[2048];      // 8 KB: readout partials, then srcOut
    ushort* srcOut = (ushort*)wredbuf;
    extern __shared__ float slab[];      // [k][32] fp32, scaled pooled features

    // 1. key load (register) + coalesced srcIn copy
    u64 key = 0ull;
    if (tid < n) {
        uint u = __float_as_uint(score[b * n + tid]);
        u = (u & 0x80000000u) ? ~u : (u | 0x80000000u);
        key = ((u64)u << 32) | (uint)(~tid);
    }
    if (tid < 512) invl[tid] = -1;
    if (do_agg) {
        const uint* s4 = (const uint*)(src_in + b * EPG);
        uint* d4 = (uint*)srcIn;
        for (int i = tid; i < EPG / 2; i += 1024) d4[i] = s4[i];
    }
    // 2. bitonic sort, descending; register-resident, shfl for in-wave rounds
    for (int kk2 = 2; kk2 <= 512; kk2 <<= 1) {
        for (int j = kk2 >> 1; j > 0; j >>= 1) {
            if (j >= 64) {
                if (tid < 512) keys[tid] = key;
                __syncthreads();
                if (tid < 512) {
                    u64 p = keys[tid ^ j];
                    bool desc = ((tid & kk2) == 0);
                    bool lower = ((tid & j) == 0);
                    u64 mx = key > p ? key : p;
                    u64 mn = key > p ? p : key;
                    key = (desc == lower) ? mx : mn;
                }
                __syncthreads();
            } else if (tid < 512) {
                u64 p = __shfl_xor(key, j);
                bool desc = ((tid & kk2) == 0);
                bool lower = ((tid & j) == 0);
                u64 mx = key > p ? key : p;
                u64 mn = key > p ? p : key;
                key = (desc == lower) ? mx : mn;
            }
        }
    }
    if (tid < 512) keys[tid] = key;
    __syncthreads();
    if (tid < k) {
        int node = (int)(~(uint)key);
        invl[node] = (short)tid;
    }
    __syncthreads();
    // 3. stage slab: scaled pooled rows, quarter channels
    for (int t = tid; t < k * 8; t += 1024) {
        int nd = t >> 3, c4 = t & 7;
        u64 kk = keys[nd];
        int node = (int)(~(uint)kk);
        float v = keyval(kk);
        uint4 u = *(const uint4*)&hp[(size_t)(b * n + node) * CCH + q * 32 + c4 * 4];
        *(float4*)&slab[nd * 32 + c4 * 4] =
            make_float4(unpk(u.x) * v, unpk(u.y) * v, unpk(u.z) * v, unpk(u.w) * v);
    }
    __syncthreads();
    // 4. readout from slab: 32 channels x 32 workers (2-way LDS, free)
    {
        int w = tid >> 5, ch = tid & 31;
        float mx = -1e30f, sm = 0.f;
        for (int r2 = w; r2 < k; r2 += 32) {
            float v = slab[r2 * 32 + ch];
            mx = fmaxf(mx, v); sm += v;
        }
        wredbuf[w * 32 + ch] = mx;
        wredbuf[1024 + w * 32 + ch] = sm;
    }
    __syncthreads();
    if (tid < 32) {
        float m = -1e30f, s = 0.f;
        for (int w = 0; w < 32; w++) {
            m = fmaxf(m, wredbuf[w * 32 + tid]);
            s += wredbuf[1024 + w * 32 + tid];
        }
        gpart[b * 256 + q * 32 + tid] = m;
        gpart[b * 256 + 128 + q * 32 + tid] = s / (float)k;
    }
    if (!do_agg) return;
    __syncthreads();   // wredbuf reads done; srcOut may now overwrite it
    // 5. compaction count (from LDS srcIn)
    int node = -1, beg = 0, c = 0, nk = 0;
    if (tid < k) {
        node = (int)(~(uint)key);
        beg = ipt_in[b * n + node] - b * EPG;
        c = cnt_in[b * n + node];
        for (int t = 0; t < c; t++)
            if (invl[srcIn[beg + t]] >= 0) nk++;
    }
    // shfl-based inclusive scan over 512 values (waves 0..7)
    {
        int lane = tid & 63;
        int v = (tid < k) ? nk : 0;
        int incl = v;
#pragma unroll
        for (int o = 1; o < 64; o <<= 1) {
            int t = __shfl_up(incl, o);
            if (lane >= o) incl += t;
        }
        if (tid < 512 && lane == 63) wtot[tid >> 6] = incl;
        __syncthreads();
        if (tid < 8) {
            int s = 0;
            for (int w = 0; w < tid; w++) s += wtot[w];
            woff[tid] = s;
        }
        __syncthreads();
        if (tid < 512) prefL[tid] = incl + woff[tid >> 6];
        __syncthreads();
    }
    int excl = (tid < 512 && tid) ? prefL[tid - 1] : 0;
    // 6. scatter srcOut (LDS)
    if (tid < k) {
        int pos = excl;
        for (int t = 0; t < c; t++) {
            int ns = invl[srcIn[beg + t]];
            if (ns >= 0) srcOut[pos++] = (ushort)ns;
        }
    }
    __syncthreads();
    // 7. q==0 writes global CSR + perm/pval
    if (q == 0) {
        int tot = prefL[511];
        if (tid < k) {
            ipt_out[b * k + tid] = b * EPG + excl;
            cnt_out[b * k + tid] = nk;
            perm_out[b * k + tid] = b * n + node;
            pval_out[b * k + tid] = keyval(key);
        }
        for (int i = tid; i < tot; i += 1024) src_out[b * EPG + i] = srcOut[i];
    }
    // 8. edge-aggregate next layer from slab (LDS CSR), 16 waves, prefetched
    {
        int wave = tid >> 6, lane = tid & 63;
        int gl = lane >> 3, sub = lane & 7;
        int ngroups = (k + 7) >> 3;
        for (int g = wave; g < ngroups; g += 16) {
            int d = g * 8 + gl;
            bool act = d < k;
            int bg = 0, en = 0;
            if (act) { bg = d ? prefL[d - 1] : 0; en = prefL[d]; }
            int cc = en - bg;
            float4 acc = make_float4(0.f, 0.f, 0.f, 0.f);
            int id_next = (cc > 0) ? (int)srcOut[bg] : 0;
            for (int j = 0; j < cc; j++) {
                int id = id_next;
                if (j + 1 < cc) id_next = (int)srcOut[bg + j + 1];
                const float4 v = *(const float4*)&slab[id * 32 + sub * 4];
                acc.x += v.x; acc.y += v.y; acc.z += v.z; acc.w += v.w;
            }
            if (act) {
                uint4 o;
                o.x = pksplit(acc.x); o.y = pksplit(acc.y);
                o.z = pksplit(acc.z); o.w = pksplit(acc.w);
                *(uint4*)&aggout[(size_t)(b * k + d) * CCH + q * 32 + sub * 4] = o;
            }
        }
    }
}

// ---------------- final MLP + log_softmax ----------------
__global__ __launch_bounds__(128) void mlp_kernel(const float* __restrict__ gpart,
        const float* __restrict__ W1, const float* __restrict__ b1,
        const float* __restrict__ W2, const float* __restrict__ b2,
        const float* __restrict__ W3, const float* __restrict__ b3,
        float* __restrict__ out) {
    int b = blockIdx.x, t = threadIdx.x;
    __shared__ float gs[256], h1[128], h2[64], lg[10];
    const float* g0 = gpart + ((size_t)0 * B_G + b) * 256;
    const float* g1 = gpart + ((size_t)1 * B_G + b) * 256;
    const float* g2 = gpart + ((size_t)2 * B_G + b) * 256;
    gs[t] = g0[t] + g1[t] + g2[t];
    gs[128 + t] = g0[128 + t] + g1[128 + t] + g2[128 + t];
    __syncthreads();
    {
        float a = b1[t];
        for (int c = 0; c < 256; c++) a += gs[c] * W1[c * 128 + t];
        h1[t] = fmaxf(a, 0.f);
    }
    __syncthreads();
    if (t < 64) {
        float a = b2[t];
        for (int c = 0; c < 128; c++) a += h1[c] * W2[c * 64 + t];
        h2[t] = fmaxf(a, 0.f);
    }
    __syncthreads();
    if (t < 10) {
        float a = b3[t];
        for (int c = 0; c < 64; c++) a += h2[c] * W3[c * 10 + t];
        lg[t] = a;
    }
    __syncthreads();
    if (t < 10) {
        float m = lg[0];
        for (int i = 1; i < 10; i++) m = fmaxf(m, lg[i]);
        float s = 0.f;
        for (int i = 0; i < 10; i++) s += expf(lg[i] - m);
        out[b * 10 + t] = lg[t] - m - logf(s);
    }
}

// ---------------- host ----------------
extern "C" void kernel_launch(void* const* d_in, const int* in_sizes, int n_in,
                              void* d_out, int out_size, void* d_ws, size_t ws_size,
                              hipStream_t stream) {
    (void)in_sizes; (void)n_in; (void)out_size; (void)ws_size;
    const float* x0 = (const float*)d_in[0];
    const int* es = (const int*)d_in[1];
    const int* ed = (const int*)d_in[2];
    const float* Wroot[3] = {(const float*)d_in[3], (const float*)d_in[7], (const float*)d_in[11]};
    const float* Wrel[3]  = {(const float*)d_in[4], (const float*)d_in[8], (const float*)d_in[12]};
    const float* brel[3]  = {(const float*)d_in[5], (const float*)d_in[9], (const float*)d_in[13]};
    const float* pvec[3]  = {(const float*)d_in[6], (const float*)d_in[10], (const float*)d_in[14]};
    const float* W1 = (const float*)d_in[15];
    const float* b1 = (const float*)d_in[16];
    const float* W2 = (const float*)d_in[17];
    const float* b2 = (const float*)d_in[18];
    const float* W3 = (const float*)d_in[19];
    const float* b3 = (const float*)d_in[20];

    size_t off = 0;
    char* base = (char*)d_ws;
    auto alloc = [&](size_t bytes) -> void* {
        void* p = base + off;
        off += (bytes + 255) & ~(size_t)255;
        return p;
    };
    const size_t FEATP = (size_t)(B_G * N0) * CCH * 4;   // packed uint plane
    uint* P0 = (uint*)alloc(FEATP);          // h planes / agg plane rotate
    uint* P1 = (uint*)alloc(FEATP);
    uint* P2 = (uint*)alloc(FEATP);
    ushort* Bph = (ushort*)alloc((size_t)3 * 32768 * 2);
    ushort* Bpl = (ushort*)alloc((size_t)3 * 32768 * 2);
    int* iptA = (int*)alloc((size_t)(B_G * N0) * 4);
    int* cntA = (int*)alloc((size_t)(B_G * N0) * 4);
    ushort* srcA = (ushort*)alloc((size_t)E_TOTAL * 2);
    int* iptB = (int*)alloc((size_t)(B_G * N0) * 4);
    int* cntB = (int*)alloc((size_t)(B_G * N0) * 4);
    ushort* srcB = (ushort*)alloc((size_t)E_TOTAL * 2);
    int* permA = (int*)alloc((size_t)(B_G * K1) * 4);
    float* pvalA = (float*)alloc((size_t)(B_G * K1) * 4);
    int* permB = (int*)alloc((size_t)(B_G * K1) * 4);
    float* pvalB = (float*)alloc((size_t)(B_G * K1) * 4);
    float* score = (float*)alloc((size_t)(B_G * N0) * 4);
    float* gpart = (float*)alloc((size_t)3 * B_G * 256 * 4);

    // setup: CSR0 + weight pack
    setup_kernel<<<B_G + (3 * 32768 + 511) / 512, 512, 0, stream>>>(
        Wrel[0], Wroot[0], Wrel[1], Wroot[1], Wrel[2], Wroot[2],
        Bph, Bpl, es, ed, iptA, cntA, srcA);

    // L0: agg from fp32 x0 -> P1 ; tf (root = fp32 x0) -> h0 in P0, score
    aggregate0<<<4 * B_G, 1024, (size_t)N0 * 32 * 4, stream>>>(
        x0, iptA, cntA, srcA, P1);
    transform_mfma<<<B_G * N0 / 128, 512, 0, stream>>>(
        P1, nullptr, x0, nullptr, nullptr, Bph, Bpl, brel[0], pvec[0], P0, score);
    // pool L0 + agg L1 -> P1 ; CSR A->B ; perm/pval A
    poolagg_kernel<<<4 * B_G, 1024, (size_t)K1 * 32 * 4, stream>>>(
        score, P0, permA, pvalA, gpart + (size_t)0 * B_G * 256,
        iptA, cntA, srcA, iptB, cntB, srcB, P1, N0, K1, 1);

    // L1: tf (A=P1, root=P0 via permA) -> h1 in P2, score
    transform_mfma<<<B_G * K1 / 128, 512, 0, stream>>>(
        P1, P0, nullptr, permA, pvalA, Bph + 32768, Bpl + 32768,
        brel[1], pvec[1], P2, score);
    // pool L1 + agg L2 -> P1 ; CSR B->A ; perm/pval B
    poolagg_kernel<<<4 * B_G, 1024, (size_t)K2 * 32 * 4, stream>>>(
        score, P2, permB, pvalB, gpart + (size_t)1 * B_G * 256,
        iptB, cntB, srcB, iptA, cntA, srcA, P1, K1, K2, 1);

    // L2: tf (A=P1, root=P2 via permB) -> h2 in P0, score
    transform_mfma<<<B_G * K2 / 128, 512, 0, stream>>>(
        P1, P2, nullptr, permB, pvalB, Bph + 2 * 32768, Bpl + 2 * 32768,
        brel[2], pvec[2], P0, score);
    // final pool: readout only
    poolagg_kernel<<<4 * B_G, 1024, (size_t)K3 * 32 * 4, stream>>>(
        score, P0, nullptr, nullptr, gpart + (size_t)2 * B_G * 256,
        iptA, cntA, srcA, nullptr, nullptr, nullptr, nullptr, K2, K3, 0);

    mlp_kernel<<<B_G, 128, 0, stream>>>(gpart, W1, b1, W2, b2, W3, b3, (float*)d_out);
}